// Round 2
// baseline (4608.132 us; speedup 1.0000x reference)
//
#include <hip/hip_runtime.h>
#include <math.h>

#define KCH 128
#define NELEM 10

__device__ __forceinline__ int lidxf(int m){ return (m==0)?0:((m<4)?1:((m<9)?2:3)); }
__device__ __forceinline__ float siluf(float z){ return z/(1.f+expf(-z)); }
__device__ __forceinline__ float dsiluf(float z){ float s=1.f/(1.f+expf(-z)); return s*(1.f+z*(1.f-s)); }

// ---------------- utility ----------------
__global__ void k_zero(float* p, int n){
  int i = blockIdx.x*256 + threadIdx.x;
  if(i<n) p[i]=0.f;
}

__global__ void k_elem(const float* attrs, int* elem, int N){
  int n = blockIdx.x*256 + threadIdx.x;
  if(n>=N) return;
  int z=0;
  for(int e=0;e<NELEM;++e) if(attrs[n*NELEM+e] > 0.5f) z=e;
  elem[n]=z;
}

__global__ void k_h0(const float* Wemb, const int* elem, float* h0, int N){
  int i = blockIdx.x*256 + threadIdx.x;
  if(i>=N*KCH) return;
  int n = i>>7, k = i&127;
  h0[i] = Wemb[elem[n]*KCH + k];
}

__global__ void k_hist(const int* keys, int* cnt, int n){
  int i = blockIdx.x*256 + threadIdx.x;
  if(i<n) atomicAdd(&cnt[keys[i]],1);
}

__global__ void k_scan(const int* cnt, int* ptr, int n){
  __shared__ int part[257];
  int t = threadIdx.x;
  int csz = (n+255)/256;
  int lo = t*csz, hi = (t+1)*csz; if(hi>n) hi=n;
  int s=0;
  for(int i=lo;i<hi;++i) s+=cnt[i];
  part[t]=s; __syncthreads();
  if(t==0){ int acc=0; for(int i=0;i<256;++i){ int v=part[i]; part[i]=acc; acc+=v; } part[256]=acc; }
  __syncthreads();
  int acc = part[t];
  for(int i=lo;i<hi;++i){ ptr[i]=acc; acc+=cnt[i]; }
  if(t==255) ptr[n]=part[256];
}

__global__ void k_scatter(const int* keys, const int* ptr, int* cur, int* idx, int n){
  int i = blockIdx.x*256 + threadIdx.x;
  if(i>=n) return;
  int k = keys[i];
  int p = atomicAdd(&cur[k],1);
  idx[ptr[k]+p] = i;
}

// batch transpose of 128x128 matrices
__global__ void k_tb(const float* src, float* dst, int nmat){
  int i = blockIdx.x*256 + threadIdx.x;
  if(i >= nmat*16384) return;
  int mat = i>>14, rc = i&16383, r = rc>>7, c = rc&127;
  dst[mat*16384 + c*128 + r] = src[i];
}

// generic transpose: dst[c*R+r] = src[r*C+c]
__global__ void k_tr(const float* src, float* dst, int R, int C){
  int i = blockIdx.x*256 + threadIdx.x;
  if(i>=R*C) return;
  int r=i/C, c=i-r*C;
  dst[c*R+r]=src[i];
}

// ---------------- precompute contracted tensors ----------------
__global__ void k_symU2(const float* U2, float* U2s){
  int i = blockIdx.x*256 + threadIdx.x;
  if(i>=1024) return;
  int p = i&3, b = (i>>2)&15, a = (i>>6)&15;
  U2s[i] = U2[a*64+b*4+p] + U2[b*64+a*4+p];
}

__global__ void k_symU3(const float* U3, float* U3s){
  int i = blockIdx.x*256 + threadIdx.x;
  if(i>=32768) return;
  int p = i&7, c = (i>>3)&15, b = (i>>7)&15, a = (i>>11)&15;
  float s = U3[a*2048+b*128+c*8+p] + U3[a*2048+c*128+b*8+p]
          + U3[b*2048+a*128+c*8+p] + U3[b*2048+c*128+a*8+p]
          + U3[c*2048+a*128+b*8+p] + U3[c*2048+b*128+a*8+p];
  U3s[i] = s;
}

__global__ void k_C1(const float* U1, const float* Wc1l, float* C1){
  int i = blockIdx.x*256 + threadIdx.x;
  if(i>=NELEM*KCH*16) return;
  int a = i&15, c = (i>>4)&127, z = i>>11;
  float s=0;
  for(int p=0;p<2;++p) s += U1[a*2+p]*Wc1l[z*2*KCH + p*KCH + c];
  C1[i]=s;
}

__global__ void k_C2S(const float* U2s, const float* Wc2l, float* C2S){
  int i = blockIdx.x*256 + threadIdx.x;
  if(i>=NELEM*KCH*256) return;
  int ab = i&255, c = (i>>8)&127, z = i>>15;
  float s=0;
  for(int p=0;p<4;++p) s += U2s[ab*4+p]*Wc2l[z*4*KCH + p*KCH + c];
  C2S[i]=s;
}

__global__ void k_T(const float* U3s, const float* Wc3l, float* T){
  int i = blockIdx.x*256 + threadIdx.x;
  if(i>=NELEM*KCH*4096) return;
  int abc = i&4095, c = (i>>12)&127, z = i>>19;
  float s=0;
  for(int p=0;p<8;++p) s += U3s[abc*8+p]*Wc3l[z*8*KCH + p*KCH + c];
  T[i]=s;
}

__global__ void k_gB1(const float* Wro, const float* Wprod1, float* gB1){
  int c = threadIdx.x;
  float s=0;
  for(int h=0;h<KCH;++h) s += Wro[h]*Wprod1[c*KCH+h];
  gB1[c]=s;
}

// ---------------- edge geometry ----------------
__global__ void k_edge_geom(const float* pos, const float* shifts, const int* ei, int E,
                            float* vec, float* rr, float* Y, float* dY, float* ef, float* defdr){
  int e = blockIdx.x*256 + threadIdx.x;
  if(e>=E) return;
  int s = ei[e], rc = ei[E+e];
  float vx = pos[rc*3+0]-pos[s*3+0]+shifts[e*3+0];
  float vy = pos[rc*3+1]-pos[s*3+1]+shifts[e*3+1];
  float vz = pos[rc*3+2]-pos[s*3+2]+shifts[e*3+2];
  float r2 = vx*vx+vy*vy+vz*vz + 1e-12f;
  float n = sqrtf(r2);
  float inv_n = 1.f/n;
  float x = vx*inv_n, y = vy*inv_n, z = vz*inv_n;
  vec[e*3+0]=vx; vec[e*3+1]=vy; vec[e*3+2]=vz; rr[e]=n;
  const float s3=1.7320508075688772f, s15=3.8729833462074170f, s5=2.2360679774997896f;
  const float s70=8.3666002653407556f, s105=10.2469507659595980f, s42=6.4807406984078604f, s7=2.6457513110645907f;
  float Yv[16], d0[16], d1[16], d2[16];
  Yv[0]=1.f; d0[0]=0;d1[0]=0;d2[0]=0;
  Yv[1]=s3*x; d0[1]=s3; d1[1]=0; d2[1]=0;
  Yv[2]=s3*y; d0[2]=0; d1[2]=s3; d2[2]=0;
  Yv[3]=s3*z; d0[3]=0; d1[3]=0; d2[3]=s3;
  Yv[4]=s15*x*y; d0[4]=s15*y; d1[4]=s15*x; d2[4]=0;
  Yv[5]=s15*y*z; d0[5]=0; d1[5]=s15*z; d2[5]=s15*y;
  Yv[6]=0.5f*s5*(3.f*z*z-1.f); d0[6]=0; d1[6]=0; d2[6]=3.f*s5*z;
  Yv[7]=s15*x*z; d0[7]=s15*z; d1[7]=0; d2[7]=s15*x;
  Yv[8]=0.5f*s15*(x*x-y*y); d0[8]=s15*x; d1[8]=-s15*y; d2[8]=0;
  Yv[9]=0.25f*s70*y*(3.f*x*x-y*y); d0[9]=1.5f*s70*x*y; d1[9]=0.75f*s70*(x*x-y*y); d2[9]=0;
  Yv[10]=s105*x*y*z; d0[10]=s105*y*z; d1[10]=s105*x*z; d2[10]=s105*x*y;
  Yv[11]=0.25f*s42*y*(5.f*z*z-1.f); d0[11]=0; d1[11]=0.25f*s42*(5.f*z*z-1.f); d2[11]=2.5f*s42*y*z;
  Yv[12]=0.5f*s7*z*(5.f*z*z-3.f); d0[12]=0; d1[12]=0; d2[12]=0.5f*s7*(15.f*z*z-3.f);
  Yv[13]=0.25f*s42*x*(5.f*z*z-1.f); d0[13]=0.25f*s42*(5.f*z*z-1.f); d1[13]=0; d2[13]=2.5f*s42*x*z;
  Yv[14]=0.5f*s105*z*(x*x-y*y); d0[14]=s105*x*z; d1[14]=-s105*y*z; d2[14]=0.5f*s105*(x*x-y*y);
  Yv[15]=0.25f*s70*x*(3.f*x*x-y*y); d0[15]=0.25f*s70*(9.f*x*x-y*y); d1[15]=-0.5f*s70*x*y; d2[15]=0;
  #pragma unroll
  for(int m=0;m<16;++m){
    float dm = d0[m]*x + d1[m]*y + d2[m]*z;
    dY[(size_t)e*48 + m*3 + 0] = (d0[m]-dm*x)*inv_n;
    dY[(size_t)e*48 + m*3 + 1] = (d1[m]-dm*y)*inv_n;
    dY[(size_t)e*48 + m*3 + 2] = (d2[m]-dm*z)*inv_n;
    Y[(size_t)e*16+m] = Yv[m];
  }
  // radial
  const float c0 = 0.63245553203367587f; // sqrt(2/5)
  float rp = n + 1e-9f;
  float u = n*0.2f;
  float f, dfdr;
  if(u < 1.f){
    float u2=u*u, u4=u2*u2, u5=u4*u, u6=u5*u, u7=u6*u;
    f = 1.f - 21.f*u5 + 35.f*u6 - 15.f*u7;
    float dfdu = -105.f*u4 + 210.f*u5 - 105.f*u6;
    dfdr = dfdu*0.2f;
  } else { f=0.f; dfdr=0.f; }
  for(int b=0;b<8;++b){
    float kn = (float)(b+1)*0.62831853071795865f; // pi/5
    float sr = sinf(kn*n), cr = cosf(kn*n);
    float bess = c0*sr/rp;
    float dbess = c0*(kn*cr/rp - sr/(rp*rp));
    ef[(size_t)e*8+b] = bess*f;
    defdr[(size_t)e*8+b] = dbess*f + bess*dfdr;
  }
}

// ---------------- small row-block matmul: Out[n,j] (+)= sum_s X[n,s]*W[s*K+j] ----------------
__global__ __launch_bounds__(128) void k_mm(const float* X, const float* W, float* Out, int N, int acc){
  __shared__ float xs[8][KCH];
  int t = threadIdx.x;
  int n0 = blockIdx.x*8;
  for(int j=0;j<8;++j){ int n=n0+j; xs[j][t] = (n<N)? X[(size_t)n*KCH+t] : 0.f; }
  __syncthreads();
  float a[8] = {0,0,0,0,0,0,0,0};
  for(int s=0;s<KCH;++s){
    float wv = W[s*KCH + t];
    #pragma unroll
    for(int j=0;j<8;++j) a[j] += xs[j][s]*wv;
  }
  for(int j=0;j<8;++j){
    int n=n0+j;
    if(n<N){ if(acc) Out[(size_t)n*KCH+t] += a[j]; else Out[(size_t)n*KCH+t] = a[j]; }
  }
}

// ---------------- radial MLP -> w (E x 512) ----------------
__global__ __launch_bounds__(256) void k_radial_w(const float* ef, const float* Wr1, const float* Wr2, const float* Wr3,
                                                  float* w, int E){
  __shared__ float t1s[16][64];
  __shared__ float t2s[16][64];
  int t = threadIdx.x;
  int e0 = blockIdx.x*16;
  for(int it=0; it<4; ++it){
    int item = t + it*256;
    int el = item>>6, j = item&63;
    float z=0;
    if(e0+el < E){
      const float* efe = ef + (size_t)(e0+el)*8;
      #pragma unroll
      for(int b=0;b<8;++b) z += efe[b]*Wr1[b*64+j];
    }
    t1s[el][j] = siluf(z);
  }
  __syncthreads();
  for(int it=0; it<4; ++it){
    int item = t + it*256;
    int el = item>>6, j = item&63;
    float z=0;
    #pragma unroll
    for(int i=0;i<64;++i) z += t1s[el][i]*Wr2[i*64+j];
    t2s[el][j] = siluf(z);
  }
  __syncthreads();
  float a0[16], a1[16];
  #pragma unroll
  for(int el=0;el<16;++el){ a0[el]=0.f; a1[el]=0.f; }
  for(int j=0;j<64;++j){
    float wa = Wr3[j*512 + t];
    float wb = Wr3[j*512 + t + 256];
    #pragma unroll
    for(int el=0;el<16;++el){
      float tv = t2s[el][j];
      a0[el] += tv*wa;
      a1[el] += tv*wb;
    }
  }
  for(int el=0;el<16;++el){
    if(e0+el < E){
      w[(size_t)(e0+el)*512 + t] = a0[el];
      w[(size_t)(e0+el)*512 + t + 256] = a1[el];
    }
  }
}

// ---------------- message aggregation (gather by recv) ----------------
__global__ __launch_bounds__(256) void k_gather(const float* hup, const float* w, const float* Y,
                                                const int* rptr, const int* ridx, const int* ei,
                                                float* agg, int E){
  int n = blockIdx.x;
  int t = threadIdx.x;
  int k = t & 127, mg = t >> 7;
  float acc[8] = {0,0,0,0,0,0,0,0};
  int s0 = rptr[n], s1 = rptr[n+1];
  for(int i=s0;i<s1;++i){
    int e = ridx[i];
    int snd = ei[e];
    float hv = hup[(size_t)snd*KCH + k];
    float4 w4 = ((const float4*)(w + (size_t)e*512))[k];
    const float* Ye = Y + (size_t)e*16 + mg*8;
    if(mg==0){
      acc[0] += w4.x*hv*Ye[0];
      acc[1] += w4.y*hv*Ye[1];
      acc[2] += w4.y*hv*Ye[2];
      acc[3] += w4.y*hv*Ye[3];
      acc[4] += w4.z*hv*Ye[4];
      acc[5] += w4.z*hv*Ye[5];
      acc[6] += w4.z*hv*Ye[6];
      acc[7] += w4.z*hv*Ye[7];
    } else {
      acc[0] += w4.z*hv*Ye[0];
      acc[1] += w4.w*hv*Ye[1];
      acc[2] += w4.w*hv*Ye[2];
      acc[3] += w4.w*hv*Ye[3];
      acc[4] += w4.w*hv*Ye[4];
      acc[5] += w4.w*hv*Ye[5];
      acc[6] += w4.w*hv*Ye[6];
      acc[7] += w4.w*hv*Ye[7];
    }
  }
  const float inv = 1.f/16.f;
  float* ap = agg + (size_t)n*2048 + k*16 + mg*8;
  #pragma unroll
  for(int j=0;j<8;++j) ap[j] = acc[j]*inv;
}

// ---------------- mixed (per-m KxK matmul) + optional skip; also used for its transpose (bwd) ----------------
__global__ __launch_bounds__(128) void k_mixed(const float* X, const float* hin, const int* elem,
                                               const float* Wl4, const float* Wskip_l,
                                               float* Out, int N, int doskip){
  __shared__ float xs[8][KCH];
  __shared__ float hs[8][KCH];
  int t = threadIdx.x;
  int m = blockIdx.y;
  int n0 = blockIdx.x*8;
  for(int j=0;j<8;++j) xs[j][t] = X[(size_t)(n0+j)*2048 + t*16 + m];
  int l = lidxf(m);
  if(doskip && m==0) for(int j=0;j<8;++j) hs[j][t] = hin[(size_t)(n0+j)*KCH + t];
  __syncthreads();
  const float* W = Wl4 + l*KCH*KCH;
  float a[8]={0,0,0,0,0,0,0,0};
  for(int s=0;s<KCH;++s){
    float wv = W[s*KCH + t];
    #pragma unroll
    for(int j=0;j<8;++j) a[j] += xs[j][s]*wv;
  }
  if(doskip && m==0){
    int zs[8];
    for(int j=0;j<8;++j) zs[j]=elem[n0+j];
    for(int s=0;s<KCH;++s){
      #pragma unroll
      for(int j=0;j<8;++j) a[j] += hs[j][s]*Wskip_l[(size_t)zs[j]*KCH*KCH + s*KCH + t];
    }
  }
  for(int j=0;j<8;++j) Out[(size_t)(n0+j)*2048 + t*16 + m] = a[j];
}

// ---------------- polynomial contraction fwd ----------------
__global__ __launch_bounds__(256) void k_poly_fwd(const float* A, const float* C1, const float* C2S, const float* T,
                                                  const int* eptr, const int* eidx, float* B){
  __shared__ float Ts[4096];
  __shared__ float C2s_[256];
  __shared__ float C1s_[16];
  int t = threadIdx.x;
  int z = blockIdx.x >> 7, c = blockIdx.x & 127;
  size_t cb = (size_t)z*KCH + c;
  for(int i=t;i<4096;i+=256) Ts[i] = T[cb*4096 + i];
  for(int i=t;i<256;i+=256) C2s_[i] = C2S[cb*256 + i];
  if(t<16) C1s_[t] = C1[cb*16 + t];
  __syncthreads();
  int s0 = eptr[z], cnt = eptr[z+1]-s0;
  for(int idx=t; idx<cnt; idx+=256){
    int n = eidx[s0+idx];
    float a[16];
    const float4* ap = (const float4*)(A + (size_t)n*2048 + c*16);
    float4 a4;
    a4=ap[0]; a[0]=a4.x;a[1]=a4.y;a[2]=a4.z;a[3]=a4.w;
    a4=ap[1]; a[4]=a4.x;a[5]=a4.y;a[6]=a4.z;a[7]=a4.w;
    a4=ap[2]; a[8]=a4.x;a[9]=a4.y;a[10]=a4.z;a[11]=a4.w;
    a4=ap[3]; a[12]=a4.x;a[13]=a4.y;a[14]=a4.z;a[15]=a4.w;
    float b1=0;
    #pragma unroll
    for(int i=0;i<16;++i) b1 += a[i]*C1s_[i];
    float b2=0;
    for(int i=0;i<16;++i){
      float s=0;
      #pragma unroll
      for(int j=0;j<16;++j) s += a[j]*C2s_[i*16+j];
      b2 += a[i]*s;
    }
    float b3=0;
    for(int i=0;i<16;++i){
      for(int j=0;j<16;++j){
        float p = a[i]*a[j];
        const float* Tp = &Ts[(i*16+j)*16];
        float s=0;
        #pragma unroll
        for(int kk=0;kk<16;++kk) s += Tp[kk]*a[kk];
        b3 += p*s;
      }
    }
    B[(size_t)n*KCH + c] = b1 + 0.5f*b2 + b3*(1.f/6.f);
  }
}

// ---------------- polynomial contraction bwd: gA = gB * d(b)/dA ----------------
__global__ __launch_bounds__(256) void k_poly_bwd(const float* A, const float* C1, const float* C2S, const float* T,
                                                  const int* eptr, const int* eidx,
                                                  const float* gBvec, const float* gBbuf, float* gA){
  __shared__ float Ts[4096];
  __shared__ float C2s_[256];
  __shared__ float C1s_[16];
  int t = threadIdx.x;
  int z = blockIdx.x >> 7, c = blockIdx.x & 127;
  size_t cb = (size_t)z*KCH + c;
  for(int i=t;i<4096;i+=256) Ts[i] = T[cb*4096 + i];
  for(int i=t;i<256;i+=256) C2s_[i] = C2S[cb*256 + i];
  if(t<16) C1s_[t] = C1[cb*16 + t];
  __syncthreads();
  int s0 = eptr[z], cnt = eptr[z+1]-s0;
  for(int idx=t; idx<cnt; idx+=256){
    int n = eidx[s0+idx];
    float a[16];
    const float4* ap = (const float4*)(A + (size_t)n*2048 + c*16);
    float4 a4;
    a4=ap[0]; a[0]=a4.x;a[1]=a4.y;a[2]=a4.z;a[3]=a4.w;
    a4=ap[1]; a[4]=a4.x;a[5]=a4.y;a[6]=a4.z;a[7]=a4.w;
    a4=ap[2]; a[8]=a4.x;a[9]=a4.y;a[10]=a4.z;a[11]=a4.w;
    a4=ap[3]; a[12]=a4.x;a[13]=a4.y;a[14]=a4.z;a[15]=a4.w;
    float gB = gBvec ? gBvec[c] : gBbuf[(size_t)n*KCH + c];
    float g12[16], g3[16];
    #pragma unroll
    for(int x=0;x<16;++x){ g12[x]=C1s_[x]; g3[x]=0.f; }
    for(int x=0;x<16;++x){
      float s=0;
      #pragma unroll
      for(int b=0;b<16;++b) s += a[b]*C2s_[x*16+b];
      g12[x]+=s;
    }
    for(int b=0;b<16;++b){
      for(int c2=0;c2<16;++c2){
        float p = a[b]*a[c2];
        const float* Tp = &Ts[(b*16+c2)*16];
        #pragma unroll
        for(int x=0;x<16;++x) g3[x] += p*Tp[x];
      }
    }
    float* gp = gA + (size_t)n*2048 + c*16;
    #pragma unroll
    for(int x=0;x<16;++x) gp[x] = gB*(g12[x] + 0.5f*g3[x]);
  }
}

// ---------------- skip backward: gh[n,k] += sum_h gA[n,h,0]*WskipT[z][h*K+k] ----------------
__global__ __launch_bounds__(128) void k_skip_bwd(const float* gA, const float* WskipT, const int* elem, float* gh){
  __shared__ float gs[KCH];
  int n = blockIdx.x, t = threadIdx.x;
  gs[t] = gA[(size_t)n*2048 + t*16];
  __syncthreads();
  int z = elem[n];
  const float* W = WskipT + (size_t)z*KCH*KCH;
  float acc=0;
  for(int h=0;h<KCH;++h) acc += gs[h]*W[h*KCH+t];
  gh[(size_t)n*KCH+t] += acc;
}

// ---------------- edge backward part A: gw, ghup, gY->gvec ----------------
// 2 edges per block; 128 k-threads per edge.
__global__ __launch_bounds__(256) void k_edge_gbwd(const float* gagg, const float* hup, const float* w,
                                                   const float* Y, const float* dY,
                                                   const int* ei, int E, int base,
                                                   float* gwc, float* ghup, float* gvec, int do_ghup){
  __shared__ float Ys[2][16];
  __shared__ float gYp[2][2][16];
  int t = threadIdx.x;
  int le = t>>7, k = t&127;
  int e = base + blockIdx.x*2 + le;
  int snd = ei[e], rcv = ei[E+e];
  if(k<16) Ys[le][k] = Y[(size_t)e*16+k];
  __syncthreads();
  float hv = hup[(size_t)snd*KCH + k];
  float4 w4 = ((const float4*)(w + (size_t)e*512))[k];
  float g[16];
  const float4* gp = (const float4*)(gagg + (size_t)rcv*2048 + k*16);
  float4 v4;
  v4=gp[0]; g[0]=v4.x;g[1]=v4.y;g[2]=v4.z;g[3]=v4.w;
  v4=gp[1]; g[4]=v4.x;g[5]=v4.y;g[6]=v4.z;g[7]=v4.w;
  v4=gp[2]; g[8]=v4.x;g[9]=v4.y;g[10]=v4.z;g[11]=v4.w;
  v4=gp[3]; g[12]=v4.x;g[13]=v4.y;g[14]=v4.z;g[15]=v4.w;
  const float inv16 = 1.f/16.f;
  const float* Yl = Ys[le];
  float p0 = g[0]*Yl[0];
  float p1 = g[1]*Yl[1]+g[2]*Yl[2]+g[3]*Yl[3];
  float p2 = g[4]*Yl[4]+g[5]*Yl[5]+g[6]*Yl[6]+g[7]*Yl[7]+g[8]*Yl[8];
  float p3 = g[9]*Yl[9]+g[10]*Yl[10]+g[11]*Yl[11]+g[12]*Yl[12]+g[13]*Yl[13]+g[14]*Yl[14]+g[15]*Yl[15];
  float hs = hv*inv16;
  float4 gwv = make_float4(p0*hs, p1*hs, p2*hs, p3*hs);
  ((float4*)(gwc + (size_t)(e-base)*512))[k] = gwv;
  if(do_ghup){
    float s = (p0*w4.x + p1*w4.y + p2*w4.z + p3*w4.w)*inv16;
    atomicAdd(&ghup[(size_t)snd*KCH+k], s);
  }
  // q[m] = g[m]*w_l(m)*hv, reduce over the 128 k-threads of this edge
  float q[16];
  q[0]=g[0]*w4.x*hv;
  q[1]=g[1]*w4.y*hv; q[2]=g[2]*w4.y*hv; q[3]=g[3]*w4.y*hv;
  q[4]=g[4]*w4.z*hv; q[5]=g[5]*w4.z*hv; q[6]=g[6]*w4.z*hv; q[7]=g[7]*w4.z*hv; q[8]=g[8]*w4.z*hv;
  #pragma unroll
  for(int m=9;m<16;++m) q[m]=g[m]*w4.w*hv;
  #pragma unroll
  for(int m=0;m<16;++m){
    float vv=q[m];
    #pragma unroll
    for(int off2=1; off2<64; off2<<=1) vv += __shfl_xor(vv, off2, 64);
    q[m]=vv;
  }
  int lane = t&63, wv2 = (t>>6)&1;
  if(lane==0){
    #pragma unroll
    for(int m=0;m<16;++m) gYp[le][wv2][m]=q[m];
  }
  __syncthreads();
  if(t<6){
    int le2 = t/3, jj = t-le2*3;
    int ee = base + blockIdx.x*2 + le2;
    float s=0;
    #pragma unroll
    for(int m=0;m<16;++m)
      s += (gYp[le2][0][m]+gYp[le2][1][m])*inv16 * dY[(size_t)ee*48 + m*3 + jj];
    gvec[ee*3+jj] += s;
  }
}

// ---------------- edge backward part B: radial MLP backward (16 edges per block) ----------------
__global__ __launch_bounds__(256) void k_radial_bwd(const float* gwc, const float* ef, const float* defdr,
                                                    const float* vec, const float* rr,
                                                    const float* Wr1, const float* Wr2,
                                                    const float* Wr2T, const float* Wr3T,
                                                    float* gvec, int base){
  __shared__ float gwS[16][512];
  __shared__ float t1s[16][64];
  __shared__ float gz2s[16][64];
  __shared__ float efS[16][8];
  __shared__ float defS[16][8];
  int t = threadIdx.x;
  int e0 = base + blockIdx.x*16;
  size_t c0 = (size_t)blockIdx.x*16*512;
  for(int r2=0;r2<32;++r2){
    int idx = r2*256 + t;
    gwS[idx>>9][idx&511] = gwc[c0 + idx];
  }
  if(t<128){ int el=t>>3, b=t&7;
    efS[el][b]=ef[(size_t)(e0+el)*8+b];
    defS[el][b]=defdr[(size_t)(e0+el)*8+b]; }
  __syncthreads();
  int j = t&63, g2 = t>>6;
  float ds1[4], ds2[4], gz1r[4];
  #pragma unroll
  for(int q=0;q<4;++q){
    int el = g2 + q*4;
    float z=0;
    #pragma unroll
    for(int b=0;b<8;++b) z += efS[el][b]*Wr1[b*64+j];
    t1s[el][j]=siluf(z); ds1[q]=dsiluf(z);
  }
  __syncthreads();
  #pragma unroll
  for(int q=0;q<4;++q){
    int el=g2+q*4;
    float z=0;
    for(int i=0;i<64;++i) z += t1s[el][i]*Wr2[i*64+j];
    ds2[q]=dsiluf(z);
  }
  #pragma unroll
  for(int q=0;q<4;++q){
    int el=g2+q*4;
    float s=0;
    for(int i=0;i<512;++i) s += gwS[el][i]*Wr3T[i*64+j];
    gz2s[el][j] = s*ds2[q];
  }
  __syncthreads();
  #pragma unroll
  for(int q=0;q<4;++q){
    int el=g2+q*4;
    float s=0;
    for(int o=0;o<64;++o) s += gz2s[el][o]*Wr2T[o*64+j];
    gz1r[q]=s*ds1[q];
  }
  #pragma unroll
  for(int q=0;q<4;++q){
    int el=g2+q*4;
    float c=0;
    #pragma unroll
    for(int b=0;b<8;++b) c += Wr1[b*64+j]*defS[el][b];
    float p = gz1r[q]*c;
    #pragma unroll
    for(int off2=1;off2<64;off2<<=1) p += __shfl_xor(p,off2,64);
    if(j<3){
      int e=e0+el;
      gvec[e*3+j] += p * vec[e*3+j] / rr[e];
    }
  }
}

// ---------------- energy readout ----------------
__global__ void k_energy(const float* h2, const float* Wro, const float* AE,
                         const int* elem, const int* batch, float* out, int N){
  int n = blockIdx.x*256 + threadIdx.x;
  if(n>=N) return;
  float s=0;
  for(int k=0;k<KCH;++k) s += h2[(size_t)n*KCH+k]*Wro[k];
  s += AE[elem[n]];
  atomicAdd(&out[batch[n]], s);
}

// ---------------- forces scatter ----------------
__global__ void k_forces(const float* gvec, const int* ei, int E, float* fout){
  int i = blockIdx.x*256 + threadIdx.x;
  if(i>=E*3) return;
  int e = i/3, j = i - e*3;
  float g = gvec[i];
  atomicAdd(&fout[(size_t)ei[e]*3+j], g);     // force[send] += dE/dvec
  atomicAdd(&fout[(size_t)ei[E+e]*3+j], -g);  // force[recv] -= dE/dvec
}

// =============================================================
extern "C" void kernel_launch(void* const* d_in, const int* in_sizes, int n_in,
                              void* d_out, int out_size, void* d_ws, size_t ws_size,
                              hipStream_t stream){
  const float* attrs  = (const float*)d_in[0];
  const float* pos    = (const float*)d_in[1];
  const float* shifts = (const float*)d_in[2];
  const float* AE     = (const float*)d_in[3];
  const float* Wemb   = (const float*)d_in[4];
  const float* Wup    = (const float*)d_in[5];
  const float* Wr1    = (const float*)d_in[6];
  const float* Wr2    = (const float*)d_in[7];
  const float* Wr3    = (const float*)d_in[8];
  const float* Wlin   = (const float*)d_in[9];
  const float* Wskip  = (const float*)d_in[10];
  const float* U1     = (const float*)d_in[11];
  const float* U2     = (const float*)d_in[12];
  const float* U3     = (const float*)d_in[13];
  const float* Wc1    = (const float*)d_in[14];
  const float* Wc2    = (const float*)d_in[15];
  const float* Wc3    = (const float*)d_in[16];
  const float* Wprod  = (const float*)d_in[17];
  const float* Wro    = (const float*)d_in[18];
  const int*   ei     = (const int*)d_in[19];
  const int*   batch  = (const int*)d_in[20];
  int N = in_sizes[1]/3;
  int E = in_sizes[19]/2;
  float* out = (float*)d_out;
  int G = out_size - 3*N;

  char* base = (char*)d_ws;
  size_t off = 0;
  auto alloc = [&](size_t nbytes)->void*{
    void* p = base + off;
    off += (nbytes + 255) & ~(size_t)255;
    return p;
  };
  int* elem = (int*)alloc((size_t)N*4);
  int* rptr = (int*)alloc((size_t)(N+1)*4);
  int* rcnt = (int*)alloc((size_t)N*4);
  int* rcur = (int*)alloc((size_t)N*4);
  int* ridx = (int*)alloc((size_t)E*4);
  int* eptr = (int*)alloc((size_t)(NELEM+1)*4);
  int* ecnt = (int*)alloc((size_t)NELEM*4);
  int* ecur = (int*)alloc((size_t)NELEM*4);
  int* eidx = (int*)alloc((size_t)N*4);
  float* h0   = (float*)alloc((size_t)N*KCH*4);
  float* h1   = (float*)alloc((size_t)N*KCH*4);
  float* h2   = (float*)alloc((size_t)N*KCH*4);
  float* hup0 = (float*)alloc((size_t)N*KCH*4);
  float* hup1 = (float*)alloc((size_t)N*KCH*4);
  float* vecb = (float*)alloc((size_t)E*3*4);
  float* rb   = (float*)alloc((size_t)E*4);
  float* Yb   = (float*)alloc((size_t)E*16*4);
  float* dYb  = (float*)alloc((size_t)E*48*4);
  float* efb  = (float*)alloc((size_t)E*8*4);
  float* defb = (float*)alloc((size_t)E*8*4);
  float* wb   = (float*)alloc((size_t)E*512*4);
  float* A0   = (float*)alloc((size_t)N*2048*4);
  float* A1   = (float*)alloc((size_t)N*2048*4);
  float* aggb = (float*)alloc((size_t)N*2048*4);  // fwd agg / bwd gagg
  float* gAb  = (float*)alloc((size_t)N*2048*4);  // poly-bwd out; reused as gw chunk buffer in edge bwd
  float* Bbuf = (float*)alloc((size_t)N*KCH*4);
  float* gh1  = (float*)alloc((size_t)N*KCH*4);
  float* ghup = (float*)alloc((size_t)N*KCH*4);
  float* gB0b = (float*)alloc((size_t)N*KCH*4);
  float* gB1v = (float*)alloc((size_t)KCH*4);
  float* gvecb= (float*)alloc((size_t)E*3*4);
  float* C1b  = (float*)alloc((size_t)NELEM*KCH*16*4);
  float* C2Sb = (float*)alloc((size_t)NELEM*KCH*256*4);
  float* Tb   = (float*)alloc((size_t)NELEM*KCH*4096*4);
  float* U2s  = (float*)alloc(1024*4);
  float* U3s  = (float*)alloc(32768*4);
  float* WupT1   = (float*)alloc(16384*4);
  float* WprodT0 = (float*)alloc(16384*4);
  float* WskipT1 = (float*)alloc((size_t)NELEM*16384*4);
  float* WlinT   = (float*)alloc((size_t)8*16384*4);
  float* Wr3T0   = (float*)alloc(32768*4);
  float* Wr3T1   = (float*)alloc(32768*4);
  float* Wr2T0   = (float*)alloc(4096*4);
  float* Wr2T1   = (float*)alloc(4096*4);
  if(off > ws_size) return; // insufficient workspace

  const int KK = KCH*KCH;           // 16384
  dim3 b256(256), b128(128);
  #define GR(n) dim3(((n)+255)/256)

  // zeros
  k_zero<<<GR(out_size),b256,0,stream>>>(out, out_size);
  k_zero<<<GR(N),b256,0,stream>>>((float*)rcnt, N);
  k_zero<<<GR(N),b256,0,stream>>>((float*)rcur, N);
  k_zero<<<GR(NELEM),b256,0,stream>>>((float*)ecnt, NELEM);
  k_zero<<<GR(NELEM),b256,0,stream>>>((float*)ecur, NELEM);
  k_zero<<<GR(N*KCH),b256,0,stream>>>(gh1, N*KCH);
  k_zero<<<GR(N*KCH),b256,0,stream>>>(ghup, N*KCH);
  k_zero<<<GR(E*3),b256,0,stream>>>(gvecb, E*3);

  // elem + embed
  k_elem<<<GR(N),b256,0,stream>>>(attrs, elem, N);
  k_h0<<<GR(N*KCH),b256,0,stream>>>(Wemb, elem, h0, N);

  // CSR by recv
  k_hist<<<GR(E),b256,0,stream>>>(ei+E, rcnt, E);
  k_scan<<<1,b256,0,stream>>>(rcnt, rptr, N);
  k_scatter<<<GR(E),b256,0,stream>>>(ei+E, rptr, rcur, ridx, E);
  // node lists by element
  k_hist<<<GR(N),b256,0,stream>>>(elem, ecnt, N);
  k_scan<<<1,b256,0,stream>>>(ecnt, eptr, NELEM);
  k_scatter<<<GR(N),b256,0,stream>>>(elem, eptr, ecur, eidx, N);

  // transposes
  k_tb<<<GR(KK),b256,0,stream>>>(Wup + KK, WupT1, 1);
  k_tb<<<GR(KK),b256,0,stream>>>(Wprod, WprodT0, 1);
  k_tb<<<GR(NELEM*KK),b256,0,stream>>>(Wskip + (size_t)NELEM*KK, WskipT1, NELEM);
  k_tb<<<GR(8*KK),b256,0,stream>>>(Wlin, WlinT, 8);
  k_tr<<<GR(32768),b256,0,stream>>>(Wr3, Wr3T0, 64, 512);
  k_tr<<<GR(32768),b256,0,stream>>>(Wr3 + 32768, Wr3T1, 64, 512);
  k_tr<<<GR(4096),b256,0,stream>>>(Wr2, Wr2T0, 64, 64);
  k_tr<<<GR(4096),b256,0,stream>>>(Wr2 + 4096, Wr2T1, 64, 64);

  // symmetrized U
  k_symU2<<<GR(1024),b256,0,stream>>>(U2, U2s);
  k_symU3<<<GR(32768),b256,0,stream>>>(U3, U3s);
  k_gB1<<<1,b128,0,stream>>>(Wro, Wprod + KK, gB1v);

  // edge geometry
  k_edge_geom<<<GR(E),b256,0,stream>>>(pos, shifts, ei, E, vecb, rb, Yb, dYb, efb, defb);

  dim3 mmG((N+7)/8);
  dim3 mixG((N+7)/8, 16);
  dim3 polyG(NELEM*KCH);
  dim3 rwG((E+15)/16);
  const int CH = 8192;   // edges per backward chunk (gw chunk = CH*512*4 = 16MB = gAb size)

  // ---------- layer 0 forward ----------
  k_C1 <<<GR(NELEM*KCH*16),  b256,0,stream>>>(U1,  Wc1, C1b);
  k_C2S<<<GR(NELEM*KCH*256), b256,0,stream>>>(U2s, Wc2, C2Sb);
  k_T  <<<GR(NELEM*KCH*4096),b256,0,stream>>>(U3s, Wc3, Tb);
  k_mm<<<mmG,b128,0,stream>>>(h0, Wup, hup0, N, 0);
  k_radial_w<<<rwG,b256,0,stream>>>(efb, Wr1, Wr2, Wr3, wb, E);
  k_gather<<<dim3(N),b256,0,stream>>>(hup0, wb, Yb, rptr, ridx, ei, aggb, E);
  k_mixed<<<mixG,b128,0,stream>>>(aggb, h0, elem, Wlin, Wskip, A0, N, 1);
  k_poly_fwd<<<polyG,b256,0,stream>>>(A0, C1b, C2Sb, Tb, eptr, eidx, Bbuf);
  k_mm<<<mmG,b128,0,stream>>>(Bbuf, Wprod, h1, N, 0);

  // ---------- layer 1 forward ----------
  k_C1 <<<GR(NELEM*KCH*16),  b256,0,stream>>>(U1,  Wc1 + NELEM*2*KCH, C1b);
  k_C2S<<<GR(NELEM*KCH*256), b256,0,stream>>>(U2s, Wc2 + NELEM*4*KCH, C2Sb);
  k_T  <<<GR(NELEM*KCH*4096),b256,0,stream>>>(U3s, Wc3 + NELEM*8*KCH, Tb);
  k_mm<<<mmG,b128,0,stream>>>(h1, Wup + KK, hup1, N, 0);
  k_radial_w<<<rwG,b256,0,stream>>>(efb, Wr1 + 512, Wr2 + 4096, Wr3 + 32768, wb, E);
  k_gather<<<dim3(N),b256,0,stream>>>(hup1, wb, Yb, rptr, ridx, ei, aggb, E);
  k_mixed<<<mixG,b128,0,stream>>>(aggb, h1, elem, Wlin + 4*KK, Wskip + (size_t)NELEM*KK, A1, N, 1);
  k_poly_fwd<<<polyG,b256,0,stream>>>(A1, C1b, C2Sb, Tb, eptr, eidx, Bbuf);
  k_mm<<<mmG,b128,0,stream>>>(Bbuf, Wprod + KK, h2, N, 0);

  // energy
  k_energy<<<GR(N),b256,0,stream>>>(h2, Wro, AE, elem, batch, out, N);

  // ---------- layer 1 backward (C buffers currently hold layer 1) ----------
  k_poly_bwd<<<polyG,b256,0,stream>>>(A1, C1b, C2Sb, Tb, eptr, eidx, gB1v, nullptr, gAb);
  k_mixed<<<mixG,b128,0,stream>>>(gAb, nullptr, elem, WlinT + 4*KK, nullptr, aggb, N, 0);
  k_skip_bwd<<<dim3(N),b128,0,stream>>>(gAb, WskipT1, elem, gh1);
  // gAb now dead -> reuse as gw chunk buffer
  for(int cb=0; cb<E; cb+=CH){
    int ce = (E-cb < CH) ? (E-cb) : CH;
    k_edge_gbwd<<<dim3(ce/2),b256,0,stream>>>(aggb, hup1, wb, Yb, dYb, ei, E, cb, gAb, ghup, gvecb, 1);
    k_radial_bwd<<<dim3(ce/16),b256,0,stream>>>(gAb, efb, defb, vecb, rb,
                                                Wr1 + 512, Wr2 + 4096, Wr2T1, Wr3T1, gvecb, cb);
  }
  k_mm<<<mmG,b128,0,stream>>>(ghup, WupT1, gh1, N, 1);

  // ---------- layer 0 backward ----------
  k_C1 <<<GR(NELEM*KCH*16),  b256,0,stream>>>(U1,  Wc1, C1b);
  k_C2S<<<GR(NELEM*KCH*256), b256,0,stream>>>(U2s, Wc2, C2Sb);
  k_T  <<<GR(NELEM*KCH*4096),b256,0,stream>>>(U3s, Wc3, Tb);
  k_mm<<<mmG,b128,0,stream>>>(gh1, WprodT0, gB0b, N, 0);
  k_poly_bwd<<<polyG,b256,0,stream>>>(A0, C1b, C2Sb, Tb, eptr, eidx, nullptr, gB0b, gAb);
  k_mixed<<<mixG,b128,0,stream>>>(gAb, nullptr, elem, WlinT, nullptr, aggb, N, 0);
  k_radial_w<<<rwG,b256,0,stream>>>(efb, Wr1, Wr2, Wr3, wb, E);
  // gAb dead again -> gw chunk buffer
  for(int cb=0; cb<E; cb+=CH){
    int ce = (E-cb < CH) ? (E-cb) : CH;
    k_edge_gbwd<<<dim3(ce/2),b256,0,stream>>>(aggb, hup0, wb, Yb, dYb, ei, E, cb, gAb, ghup, gvecb, 0);
    k_radial_bwd<<<dim3(ce/16),b256,0,stream>>>(gAb, efb, defb, vecb, rb,
                                                Wr1, Wr2, Wr2T0, Wr3T0, gvecb, cb);
  }

  // forces
  k_forces<<<GR(E*3),b256,0,stream>>>(gvecb, ei, E, out + G);
  #undef GR
}

// Round 3
// 1851.813 us; speedup vs baseline: 2.4884x; 2.4884x over previous
//
#include <hip/hip_runtime.h>
#include <math.h>

#define KCH 128
#define NELEM 10

__device__ __forceinline__ int lidxf(int m){ return (m==0)?0:((m<4)?1:((m<9)?2:3)); }
__device__ __forceinline__ float siluf(float z){ return z/(1.f+expf(-z)); }
__device__ __forceinline__ float dsiluf(float z){ float s=1.f/(1.f+expf(-z)); return s*(1.f+z*(1.f-s)); }

// ---------------- utility ----------------
__global__ void k_zero(float* p, int n){
  int i = blockIdx.x*256 + threadIdx.x;
  if(i<n) p[i]=0.f;
}

__global__ void k_elem(const float* attrs, int* elem, int N){
  int n = blockIdx.x*256 + threadIdx.x;
  if(n>=N) return;
  int z=0;
  for(int e=0;e<NELEM;++e) if(attrs[n*NELEM+e] > 0.5f) z=e;
  elem[n]=z;
}

__global__ void k_h0(const float* Wemb, const int* elem, float* h0, int N){
  int i = blockIdx.x*256 + threadIdx.x;
  if(i>=N*KCH) return;
  int n = i>>7, k = i&127;
  h0[i] = Wemb[elem[n]*KCH + k];
}

__global__ void k_hist(const int* keys, int* cnt, int n){
  int i = blockIdx.x*256 + threadIdx.x;
  if(i<n) atomicAdd(&cnt[keys[i]],1);
}

__global__ void k_scan(const int* cnt, int* ptr, int n){
  __shared__ int part[257];
  int t = threadIdx.x;
  int csz = (n+255)/256;
  int lo = t*csz, hi = (t+1)*csz; if(hi>n) hi=n;
  int s=0;
  for(int i=lo;i<hi;++i) s+=cnt[i];
  part[t]=s; __syncthreads();
  if(t==0){ int acc=0; for(int i=0;i<256;++i){ int v=part[i]; part[i]=acc; acc+=v; } part[256]=acc; }
  __syncthreads();
  int acc = part[t];
  for(int i=lo;i<hi;++i){ ptr[i]=acc; acc+=cnt[i]; }
  if(t==255) ptr[n]=part[256];
}

__global__ void k_scatter(const int* keys, const int* ptr, int* cur, int* idx, int n){
  int i = blockIdx.x*256 + threadIdx.x;
  if(i>=n) return;
  int k = keys[i];
  int p = atomicAdd(&cur[k],1);
  idx[ptr[k]+p] = i;
}

// batch transpose of 128x128 matrices
__global__ void k_tb(const float* src, float* dst, int nmat){
  int i = blockIdx.x*256 + threadIdx.x;
  if(i >= nmat*16384) return;
  int mat = i>>14, rc = i&16383, r = rc>>7, c = rc&127;
  dst[mat*16384 + c*128 + r] = src[i];
}

// generic transpose: dst[c*R+r] = src[r*C+c]
__global__ void k_tr(const float* src, float* dst, int R, int C){
  int i = blockIdx.x*256 + threadIdx.x;
  if(i>=R*C) return;
  int r=i/C, c=i-r*C;
  dst[c*R+r]=src[i];
}

// ---------------- precompute contracted tensors ----------------
__global__ void k_symU2(const float* U2, float* U2s){
  int i = blockIdx.x*256 + threadIdx.x;
  if(i>=1024) return;
  int p = i&3, b = (i>>2)&15, a = (i>>6)&15;
  U2s[i] = U2[a*64+b*4+p] + U2[b*64+a*4+p];
}

__global__ void k_symU3(const float* U3, float* U3s){
  int i = blockIdx.x*256 + threadIdx.x;
  if(i>=32768) return;
  int p = i&7, c = (i>>3)&15, b = (i>>7)&15, a = (i>>11)&15;
  float s = U3[a*2048+b*128+c*8+p] + U3[a*2048+c*128+b*8+p]
          + U3[b*2048+a*128+c*8+p] + U3[b*2048+c*128+a*8+p]
          + U3[c*2048+a*128+b*8+p] + U3[c*2048+b*128+a*8+p];
  U3s[i] = s;
}

__global__ void k_C1(const float* U1, const float* Wc1l, float* C1){
  int i = blockIdx.x*256 + threadIdx.x;
  if(i>=NELEM*KCH*16) return;
  int a = i&15, c = (i>>4)&127, z = i>>11;
  float s=0;
  for(int p=0;p<2;++p) s += U1[a*2+p]*Wc1l[z*2*KCH + p*KCH + c];
  C1[i]=s;
}

__global__ void k_C2S(const float* U2s, const float* Wc2l, float* C2S){
  int i = blockIdx.x*256 + threadIdx.x;
  if(i>=NELEM*KCH*256) return;
  int ab = i&255, c = (i>>8)&127, z = i>>15;
  float s=0;
  for(int p=0;p<4;++p) s += U2s[ab*4+p]*Wc2l[z*4*KCH + p*KCH + c];
  C2S[i]=s;
}

__global__ void k_T(const float* U3s, const float* Wc3l, float* T){
  int i = blockIdx.x*256 + threadIdx.x;
  if(i>=NELEM*KCH*4096) return;
  int abc = i&4095, c = (i>>12)&127, z = i>>19;
  float s=0;
  for(int p=0;p<8;++p) s += U3s[abc*8+p]*Wc3l[z*8*KCH + p*KCH + c];
  T[i]=s;
}

__global__ void k_gB1(const float* Wro, const float* Wprod1, float* gB1){
  int c = threadIdx.x;
  float s=0;
  for(int h=0;h<KCH;++h) s += Wro[h]*Wprod1[c*KCH+h];
  gB1[c]=s;
}

// ---------------- edge geometry ----------------
__global__ void k_edge_geom(const float* pos, const float* shifts, const int* ei, int E,
                            float* vec, float* rr, float* Y, float* dY, float* ef, float* defdr){
  int e = blockIdx.x*256 + threadIdx.x;
  if(e>=E) return;
  int s = ei[e], rc = ei[E+e];
  float vx = pos[rc*3+0]-pos[s*3+0]+shifts[e*3+0];
  float vy = pos[rc*3+1]-pos[s*3+1]+shifts[e*3+1];
  float vz = pos[rc*3+2]-pos[s*3+2]+shifts[e*3+2];
  float r2 = vx*vx+vy*vy+vz*vz + 1e-12f;
  float n = sqrtf(r2);
  float inv_n = 1.f/n;
  float x = vx*inv_n, y = vy*inv_n, z = vz*inv_n;
  vec[e*3+0]=vx; vec[e*3+1]=vy; vec[e*3+2]=vz; rr[e]=n;
  const float s3=1.7320508075688772f, s15=3.8729833462074170f, s5=2.2360679774997896f;
  const float s70=8.3666002653407556f, s105=10.2469507659595980f, s42=6.4807406984078604f, s7=2.6457513110645907f;
  float Yv[16], d0[16], d1[16], d2[16];
  Yv[0]=1.f; d0[0]=0;d1[0]=0;d2[0]=0;
  Yv[1]=s3*x; d0[1]=s3; d1[1]=0; d2[1]=0;
  Yv[2]=s3*y; d0[2]=0; d1[2]=s3; d2[2]=0;
  Yv[3]=s3*z; d0[3]=0; d1[3]=0; d2[3]=s3;
  Yv[4]=s15*x*y; d0[4]=s15*y; d1[4]=s15*x; d2[4]=0;
  Yv[5]=s15*y*z; d0[5]=0; d1[5]=s15*z; d2[5]=s15*y;
  Yv[6]=0.5f*s5*(3.f*z*z-1.f); d0[6]=0; d1[6]=0; d2[6]=3.f*s5*z;
  Yv[7]=s15*x*z; d0[7]=s15*z; d1[7]=0; d2[7]=s15*x;
  Yv[8]=0.5f*s15*(x*x-y*y); d0[8]=s15*x; d1[8]=-s15*y; d2[8]=0;
  Yv[9]=0.25f*s70*y*(3.f*x*x-y*y); d0[9]=1.5f*s70*x*y; d1[9]=0.75f*s70*(x*x-y*y); d2[9]=0;
  Yv[10]=s105*x*y*z; d0[10]=s105*y*z; d1[10]=s105*x*z; d2[10]=s105*x*y;
  Yv[11]=0.25f*s42*y*(5.f*z*z-1.f); d0[11]=0; d1[11]=0.25f*s42*(5.f*z*z-1.f); d2[11]=2.5f*s42*y*z;
  Yv[12]=0.5f*s7*z*(5.f*z*z-3.f); d0[12]=0; d1[12]=0; d2[12]=0.5f*s7*(15.f*z*z-3.f);
  Yv[13]=0.25f*s42*x*(5.f*z*z-1.f); d0[13]=0.25f*s42*(5.f*z*z-1.f); d1[13]=0; d2[13]=2.5f*s42*x*z;
  Yv[14]=0.5f*s105*z*(x*x-y*y); d0[14]=s105*x*z; d1[14]=-s105*y*z; d2[14]=0.5f*s105*(x*x-y*y);
  Yv[15]=0.25f*s70*x*(3.f*x*x-y*y); d0[15]=0.25f*s70*(9.f*x*x-y*y); d1[15]=-0.5f*s70*x*y; d2[15]=0;
  #pragma unroll
  for(int m=0;m<16;++m){
    float dm = d0[m]*x + d1[m]*y + d2[m]*z;
    dY[(size_t)e*48 + m*3 + 0] = (d0[m]-dm*x)*inv_n;
    dY[(size_t)e*48 + m*3 + 1] = (d1[m]-dm*y)*inv_n;
    dY[(size_t)e*48 + m*3 + 2] = (d2[m]-dm*z)*inv_n;
    Y[(size_t)e*16+m] = Yv[m];
  }
  // radial
  const float c0 = 0.63245553203367587f; // sqrt(2/5)
  float rp = n + 1e-9f;
  float u = n*0.2f;
  float f, dfdr;
  if(u < 1.f){
    float u2=u*u, u4=u2*u2, u5=u4*u, u6=u5*u, u7=u6*u;
    f = 1.f - 21.f*u5 + 35.f*u6 - 15.f*u7;
    float dfdu = -105.f*u4 + 210.f*u5 - 105.f*u6;
    dfdr = dfdu*0.2f;
  } else { f=0.f; dfdr=0.f; }
  for(int b=0;b<8;++b){
    float kn = (float)(b+1)*0.62831853071795865f; // pi/5
    float sr = sinf(kn*n), cr = cosf(kn*n);
    float bess = c0*sr/rp;
    float dbess = c0*(kn*cr/rp - sr/(rp*rp));
    ef[(size_t)e*8+b] = bess*f;
    defdr[(size_t)e*8+b] = dbess*f + bess*dfdr;
  }
}

// ---------------- small row-block matmul: Out[n,j] (+)= sum_s X[n,s]*W[s*K+j] ----------------
__global__ __launch_bounds__(128) void k_mm(const float* X, const float* W, float* Out, int N, int acc){
  __shared__ float xs[8][KCH];
  int t = threadIdx.x;
  int n0 = blockIdx.x*8;
  for(int j=0;j<8;++j){ int n=n0+j; xs[j][t] = (n<N)? X[(size_t)n*KCH+t] : 0.f; }
  __syncthreads();
  float a[8] = {0,0,0,0,0,0,0,0};
  for(int s=0;s<KCH;++s){
    float wv = W[s*KCH + t];
    #pragma unroll
    for(int j=0;j<8;++j) a[j] += xs[j][s]*wv;
  }
  for(int j=0;j<8;++j){
    int n=n0+j;
    if(n<N){ if(acc) Out[(size_t)n*KCH+t] += a[j]; else Out[(size_t)n*KCH+t] = a[j]; }
  }
}

// ---------------- radial MLP -> w (E x 512) ----------------
__global__ __launch_bounds__(256) void k_radial_w(const float* ef, const float* Wr1, const float* Wr2, const float* Wr3,
                                                  float* w, int E){
  __shared__ float t1s[16][64];
  __shared__ float t2s[16][64];
  int t = threadIdx.x;
  int e0 = blockIdx.x*16;
  for(int it=0; it<4; ++it){
    int item = t + it*256;
    int el = item>>6, j = item&63;
    float z=0;
    if(e0+el < E){
      const float* efe = ef + (size_t)(e0+el)*8;
      #pragma unroll
      for(int b=0;b<8;++b) z += efe[b]*Wr1[b*64+j];
    }
    t1s[el][j] = siluf(z);
  }
  __syncthreads();
  for(int it=0; it<4; ++it){
    int item = t + it*256;
    int el = item>>6, j = item&63;
    float z=0;
    #pragma unroll
    for(int i=0;i<64;++i) z += t1s[el][i]*Wr2[i*64+j];
    t2s[el][j] = siluf(z);
  }
  __syncthreads();
  float a0[16], a1[16];
  #pragma unroll
  for(int el=0;el<16;++el){ a0[el]=0.f; a1[el]=0.f; }
  for(int j=0;j<64;++j){
    float wa = Wr3[j*512 + t];
    float wb = Wr3[j*512 + t + 256];
    #pragma unroll
    for(int el=0;el<16;++el){
      float tv = t2s[el][j];
      a0[el] += tv*wa;
      a1[el] += tv*wb;
    }
  }
  for(int el=0;el<16;++el){
    if(e0+el < E){
      w[(size_t)(e0+el)*512 + t] = a0[el];
      w[(size_t)(e0+el)*512 + t + 256] = a1[el];
    }
  }
}

// ---------------- message aggregation (gather by recv) ----------------
__global__ __launch_bounds__(256) void k_gather(const float* hup, const float* w, const float* Y,
                                                const int* rptr, const int* ridx, const int* ei,
                                                float* agg, int E){
  int n = blockIdx.x;
  int t = threadIdx.x;
  int k = t & 127, mg = t >> 7;
  float acc[8] = {0,0,0,0,0,0,0,0};
  int s0 = rptr[n], s1 = rptr[n+1];
  for(int i=s0;i<s1;++i){
    int e = ridx[i];
    int snd = ei[e];
    float hv = hup[(size_t)snd*KCH + k];
    float4 w4 = ((const float4*)(w + (size_t)e*512))[k];
    const float* Ye = Y + (size_t)e*16 + mg*8;
    if(mg==0){
      acc[0] += w4.x*hv*Ye[0];
      acc[1] += w4.y*hv*Ye[1];
      acc[2] += w4.y*hv*Ye[2];
      acc[3] += w4.y*hv*Ye[3];
      acc[4] += w4.z*hv*Ye[4];
      acc[5] += w4.z*hv*Ye[5];
      acc[6] += w4.z*hv*Ye[6];
      acc[7] += w4.z*hv*Ye[7];
    } else {
      acc[0] += w4.z*hv*Ye[0];
      acc[1] += w4.w*hv*Ye[1];
      acc[2] += w4.w*hv*Ye[2];
      acc[3] += w4.w*hv*Ye[3];
      acc[4] += w4.w*hv*Ye[4];
      acc[5] += w4.w*hv*Ye[5];
      acc[6] += w4.w*hv*Ye[6];
      acc[7] += w4.w*hv*Ye[7];
    }
  }
  const float inv = 1.f/16.f;
  float* ap = agg + (size_t)n*2048 + k*16 + mg*8;
  #pragma unroll
  for(int j=0;j<8;++j) ap[j] = acc[j]*inv;
}

// ---------------- mixed (per-m KxK matmul) + optional skip; also used for its transpose (bwd) ----------------
__global__ __launch_bounds__(128) void k_mixed(const float* X, const float* hin, const int* elem,
                                               const float* Wl4, const float* Wskip_l,
                                               float* Out, int N, int doskip){
  __shared__ float xs[8][KCH];
  __shared__ float hs[8][KCH];
  int t = threadIdx.x;
  int m = blockIdx.y;
  int n0 = blockIdx.x*8;
  for(int j=0;j<8;++j) xs[j][t] = X[(size_t)(n0+j)*2048 + t*16 + m];
  int l = lidxf(m);
  if(doskip && m==0) for(int j=0;j<8;++j) hs[j][t] = hin[(size_t)(n0+j)*KCH + t];
  __syncthreads();
  const float* W = Wl4 + l*KCH*KCH;
  float a[8]={0,0,0,0,0,0,0,0};
  for(int s=0;s<KCH;++s){
    float wv = W[s*KCH + t];
    #pragma unroll
    for(int j=0;j<8;++j) a[j] += xs[j][s]*wv;
  }
  if(doskip && m==0){
    int zs[8];
    for(int j=0;j<8;++j) zs[j]=elem[n0+j];
    for(int s=0;s<KCH;++s){
      #pragma unroll
      for(int j=0;j<8;++j) a[j] += hs[j][s]*Wskip_l[(size_t)zs[j]*KCH*KCH + s*KCH + t];
    }
  }
  for(int j=0;j<8;++j) Out[(size_t)(n0+j)*2048 + t*16 + m] = a[j];
}

// ---------------- polynomial contraction fwd ----------------
__global__ __launch_bounds__(256) void k_poly_fwd(const float* A, const float* C1, const float* C2S, const float* T,
                                                  const int* eptr, const int* eidx, float* B){
  __shared__ float Ts[4096];
  __shared__ float C2s_[256];
  __shared__ float C1s_[16];
  int t = threadIdx.x;
  int z = blockIdx.x >> 7, c = blockIdx.x & 127;
  size_t cb = (size_t)z*KCH + c;
  for(int i=t;i<4096;i+=256) Ts[i] = T[cb*4096 + i];
  for(int i=t;i<256;i+=256) C2s_[i] = C2S[cb*256 + i];
  if(t<16) C1s_[t] = C1[cb*16 + t];
  __syncthreads();
  int s0 = eptr[z], cnt = eptr[z+1]-s0;
  for(int idx=t; idx<cnt; idx+=256){
    int n = eidx[s0+idx];
    float a[16];
    const float4* ap = (const float4*)(A + (size_t)n*2048 + c*16);
    float4 a4;
    a4=ap[0]; a[0]=a4.x;a[1]=a4.y;a[2]=a4.z;a[3]=a4.w;
    a4=ap[1]; a[4]=a4.x;a[5]=a4.y;a[6]=a4.z;a[7]=a4.w;
    a4=ap[2]; a[8]=a4.x;a[9]=a4.y;a[10]=a4.z;a[11]=a4.w;
    a4=ap[3]; a[12]=a4.x;a[13]=a4.y;a[14]=a4.z;a[15]=a4.w;
    float b1=0;
    #pragma unroll
    for(int i=0;i<16;++i) b1 += a[i]*C1s_[i];
    float b2=0;
    for(int i=0;i<16;++i){
      float s=0;
      #pragma unroll
      for(int j=0;j<16;++j) s += a[j]*C2s_[i*16+j];
      b2 += a[i]*s;
    }
    float b3=0;
    for(int i=0;i<16;++i){
      for(int j=0;j<16;++j){
        float p = a[i]*a[j];
        const float* Tp = &Ts[(i*16+j)*16];
        float s=0;
        #pragma unroll
        for(int kk=0;kk<16;++kk) s += Tp[kk]*a[kk];
        b3 += p*s;
      }
    }
    B[(size_t)n*KCH + c] = b1 + 0.5f*b2 + b3*(1.f/6.f);
  }
}

// ---------------- polynomial contraction bwd: gA = gB * d(b)/dA ----------------
__global__ __launch_bounds__(256) void k_poly_bwd(const float* A, const float* C1, const float* C2S, const float* T,
                                                  const int* eptr, const int* eidx,
                                                  const float* gBvec, const float* gBbuf, float* gA){
  __shared__ float Ts[4096];
  __shared__ float C2s_[256];
  __shared__ float C1s_[16];
  int t = threadIdx.x;
  int z = blockIdx.x >> 7, c = blockIdx.x & 127;
  size_t cb = (size_t)z*KCH + c;
  for(int i=t;i<4096;i+=256) Ts[i] = T[cb*4096 + i];
  for(int i=t;i<256;i+=256) C2s_[i] = C2S[cb*256 + i];
  if(t<16) C1s_[t] = C1[cb*16 + t];
  __syncthreads();
  int s0 = eptr[z], cnt = eptr[z+1]-s0;
  for(int idx=t; idx<cnt; idx+=256){
    int n = eidx[s0+idx];
    float a[16];
    const float4* ap = (const float4*)(A + (size_t)n*2048 + c*16);
    float4 a4;
    a4=ap[0]; a[0]=a4.x;a[1]=a4.y;a[2]=a4.z;a[3]=a4.w;
    a4=ap[1]; a[4]=a4.x;a[5]=a4.y;a[6]=a4.z;a[7]=a4.w;
    a4=ap[2]; a[8]=a4.x;a[9]=a4.y;a[10]=a4.z;a[11]=a4.w;
    a4=ap[3]; a[12]=a4.x;a[13]=a4.y;a[14]=a4.z;a[15]=a4.w;
    float gB = gBvec ? gBvec[c] : gBbuf[(size_t)n*KCH + c];
    float g12[16], g3[16];
    #pragma unroll
    for(int x=0;x<16;++x){ g12[x]=C1s_[x]; g3[x]=0.f; }
    for(int x=0;x<16;++x){
      float s=0;
      #pragma unroll
      for(int b=0;b<16;++b) s += a[b]*C2s_[x*16+b];
      g12[x]+=s;
    }
    for(int b=0;b<16;++b){
      for(int c2=0;c2<16;++c2){
        float p = a[b]*a[c2];
        const float* Tp = &Ts[(b*16+c2)*16];
        #pragma unroll
        for(int x=0;x<16;++x) g3[x] += p*Tp[x];
      }
    }
    float* gp = gA + (size_t)n*2048 + c*16;
    #pragma unroll
    for(int x=0;x<16;++x) gp[x] = gB*(g12[x] + 0.5f*g3[x]);
  }
}

// ---------------- skip backward: gh[n,k] += sum_h gA[n,h,0]*WskipT[z][h*K+k] ----------------
__global__ __launch_bounds__(128) void k_skip_bwd(const float* gA, const float* WskipT, const int* elem, float* gh){
  __shared__ float gs[KCH];
  int n = blockIdx.x, t = threadIdx.x;
  gs[t] = gA[(size_t)n*2048 + t*16];
  __syncthreads();
  int z = elem[n];
  const float* W = WskipT + (size_t)z*KCH*KCH;
  float acc=0;
  for(int h=0;h<KCH;++h) acc += gs[h]*W[h*KCH+t];
  gh[(size_t)n*KCH+t] += acc;
}

// ---------------- fused edge backward: 4 edges per block ----------------
// Phase A (2 reps x 128 k-threads/edge): gw -> LDS, ghup atomics, gY partials.
// Phase B (1 wave per edge): radial MLP backward from LDS gw, gvec write.
__global__ __launch_bounds__(256) void k_edge_bwd2(const float* gagg, const float* hup, const float* w,
                                                   const float* Y, const float* dY,
                                                   const float* vec, const float* rr,
                                                   const float* ef, const float* defdr,
                                                   const float* Wr1, const float* Wr2,
                                                   const float* Wr2T, const float* Wr3T,
                                                   const int* ei, int E,
                                                   float* ghup, float* gvec, int do_ghup){
  __shared__ float Ys[4][16];
  __shared__ float gwS[4][512];
  __shared__ float gYp[4][2][16];
  __shared__ float t1s[4][64];
  __shared__ float gz2s[4][64];
  __shared__ float efS[4][8];
  __shared__ float defS[4][8];
  int t = threadIdx.x;
  int e0 = blockIdx.x*4;
  const float inv16 = 1.f/16.f;
  // preload small per-edge data
  if(t<64){ int le=t>>4; int ec = e0+le; if(ec<E) Ys[le][t&15] = Y[(size_t)ec*16 + (t&15)]; }
  else if(t<96){ int i=t-64; int le=i>>3; int ec=e0+le; if(ec<E) efS[le][i&7]=ef[(size_t)ec*8+(i&7)]; }
  else if(t<128){ int i=t-96; int le=i>>3; int ec=e0+le; if(ec<E) defS[le][i&7]=defdr[(size_t)ec*8+(i&7)]; }
  __syncthreads();
  for(int rep=0;rep<2;++rep){
    int le = (t>>7) + 2*rep;
    int k = t&127;
    int e = e0+le;
    bool valid = (e<E);
    int eC = valid ? e : (E-1);
    int snd = ei[eC], rcv = ei[E+eC];
    float hv = hup[(size_t)snd*KCH + k];
    float4 w4 = ((const float4*)(w + (size_t)eC*512))[k];
    float g[16];
    const float4* gp = (const float4*)(gagg + (size_t)rcv*2048 + k*16);
    float4 v4;
    v4=gp[0]; g[0]=v4.x;g[1]=v4.y;g[2]=v4.z;g[3]=v4.w;
    v4=gp[1]; g[4]=v4.x;g[5]=v4.y;g[6]=v4.z;g[7]=v4.w;
    v4=gp[2]; g[8]=v4.x;g[9]=v4.y;g[10]=v4.z;g[11]=v4.w;
    v4=gp[3]; g[12]=v4.x;g[13]=v4.y;g[14]=v4.z;g[15]=v4.w;
    const float* Yl = Ys[le];
    float p0 = g[0]*Yl[0];
    float p1 = g[1]*Yl[1]+g[2]*Yl[2]+g[3]*Yl[3];
    float p2 = g[4]*Yl[4]+g[5]*Yl[5]+g[6]*Yl[6]+g[7]*Yl[7]+g[8]*Yl[8];
    float p3 = g[9]*Yl[9]+g[10]*Yl[10]+g[11]*Yl[11]+g[12]*Yl[12]+g[13]*Yl[13]+g[14]*Yl[14]+g[15]*Yl[15];
    float hs = hv*inv16;
    ((float4*)(&gwS[le][k*4]))[0] = make_float4(p0*hs, p1*hs, p2*hs, p3*hs);
    if(do_ghup && valid){
      float s = (p0*w4.x + p1*w4.y + p2*w4.z + p3*w4.w)*inv16;
      atomicAdd(&ghup[(size_t)snd*KCH+k], s);
    }
    // q[m] = g[m]*w_l(m)*hv, butterfly reduce over 64 lanes (2 waves per edge)
    float q[16];
    q[0]=g[0]*w4.x*hv;
    q[1]=g[1]*w4.y*hv; q[2]=g[2]*w4.y*hv; q[3]=g[3]*w4.y*hv;
    q[4]=g[4]*w4.z*hv; q[5]=g[5]*w4.z*hv; q[6]=g[6]*w4.z*hv; q[7]=g[7]*w4.z*hv; q[8]=g[8]*w4.z*hv;
    #pragma unroll
    for(int m=9;m<16;++m) q[m]=g[m]*w4.w*hv;
    #pragma unroll
    for(int m=0;m<16;++m){
      float vv=q[m];
      #pragma unroll
      for(int off2=1; off2<64; off2<<=1) vv += __shfl_xor(vv, off2, 64);
      q[m]=vv;
    }
    if((t&63)==0){
      int wv2 = (t>>6)&1;
      #pragma unroll
      for(int m=0;m<16;++m) gYp[le][wv2][m]=q[m];
    }
  }
  __syncthreads();
  // Phase B: one wave per edge
  {
    int el = t>>6, j = t&63;
    int e = e0+el;
    bool valid = (e<E);
    int eC = valid ? e : (E-1);
    float z1=0;
    #pragma unroll
    for(int b=0;b<8;++b) z1 += efS[el][b]*Wr1[b*64+j];
    float ds1v = dsiluf(z1);
    t1s[el][j] = siluf(z1);
    __syncthreads();
    float z2=0;
    for(int i=0;i<64;++i) z2 += t1s[el][i]*Wr2[i*64+j];
    float ds2v = dsiluf(z2);
    float gt2=0;
    for(int i=0;i<512;++i) gt2 += gwS[el][i]*Wr3T[i*64+j];
    gz2s[el][j] = gt2*ds2v;
    __syncthreads();
    float gz1=0;
    for(int o=0;o<64;++o) gz1 += gz2s[el][o]*Wr2T[o*64+j];
    gz1 *= ds1v;
    float cj=0;
    #pragma unroll
    for(int b=0;b<8;++b) cj += Wr1[b*64+j]*defS[el][b];
    float p = gz1*cj;
    #pragma unroll
    for(int off2=1;off2<64;off2<<=1) p += __shfl_xor(p,off2,64);
    if(j<3 && valid){
      float s = p * vec[(size_t)eC*3+j] / rr[eC];
      #pragma unroll
      for(int m=0;m<16;++m)
        s += (gYp[el][0][m]+gYp[el][1][m])*inv16 * dY[(size_t)eC*48 + m*3 + j];
      gvec[(size_t)eC*3+j] += s;
    }
  }
}

// ---------------- energy readout ----------------
__global__ void k_energy(const float* h2, const float* Wro, const float* AE,
                         const int* elem, const int* batch, float* out, int N){
  int n = blockIdx.x*256 + threadIdx.x;
  if(n>=N) return;
  float s=0;
  for(int k=0;k<KCH;++k) s += h2[(size_t)n*KCH+k]*Wro[k];
  s += AE[elem[n]];
  atomicAdd(&out[batch[n]], s);
}

// ---------------- forces scatter ----------------
__global__ void k_forces(const float* gvec, const int* ei, int E, float* fout){
  int i = blockIdx.x*256 + threadIdx.x;
  if(i>=E*3) return;
  int e = i/3, j = i - e*3;
  float g = gvec[i];
  atomicAdd(&fout[(size_t)ei[e]*3+j], g);     // force[send] += dE/dvec
  atomicAdd(&fout[(size_t)ei[E+e]*3+j], -g);  // force[recv] -= dE/dvec
}

// =============================================================
extern "C" void kernel_launch(void* const* d_in, const int* in_sizes, int n_in,
                              void* d_out, int out_size, void* d_ws, size_t ws_size,
                              hipStream_t stream){
  const float* attrs  = (const float*)d_in[0];
  const float* pos    = (const float*)d_in[1];
  const float* shifts = (const float*)d_in[2];
  const float* AE     = (const float*)d_in[3];
  const float* Wemb   = (const float*)d_in[4];
  const float* Wup    = (const float*)d_in[5];
  const float* Wr1    = (const float*)d_in[6];
  const float* Wr2    = (const float*)d_in[7];
  const float* Wr3    = (const float*)d_in[8];
  const float* Wlin   = (const float*)d_in[9];
  const float* Wskip  = (const float*)d_in[10];
  const float* U1     = (const float*)d_in[11];
  const float* U2     = (const float*)d_in[12];
  const float* U3     = (const float*)d_in[13];
  const float* Wc1    = (const float*)d_in[14];
  const float* Wc2    = (const float*)d_in[15];
  const float* Wc3    = (const float*)d_in[16];
  const float* Wprod  = (const float*)d_in[17];
  const float* Wro    = (const float*)d_in[18];
  const int*   ei     = (const int*)d_in[19];
  const int*   batch  = (const int*)d_in[20];
  int N = in_sizes[1]/3;
  int E = in_sizes[19]/2;
  float* out = (float*)d_out;
  int G = out_size - 3*N;

  char* base = (char*)d_ws;
  size_t off = 0;
  auto alloc = [&](size_t nbytes)->void*{
    void* p = base + off;
    off += (nbytes + 255) & ~(size_t)255;
    return p;
  };
  int* elem = (int*)alloc((size_t)N*4);
  int* rptr = (int*)alloc((size_t)(N+1)*4);
  int* rcnt = (int*)alloc((size_t)N*4);
  int* rcur = (int*)alloc((size_t)N*4);
  int* ridx = (int*)alloc((size_t)E*4);
  int* eptr = (int*)alloc((size_t)(NELEM+1)*4);
  int* ecnt = (int*)alloc((size_t)NELEM*4);
  int* ecur = (int*)alloc((size_t)NELEM*4);
  int* eidx = (int*)alloc((size_t)N*4);
  float* h0   = (float*)alloc((size_t)N*KCH*4);
  float* h1   = (float*)alloc((size_t)N*KCH*4);
  float* h2   = (float*)alloc((size_t)N*KCH*4);
  float* hup0 = (float*)alloc((size_t)N*KCH*4);
  float* hup1 = (float*)alloc((size_t)N*KCH*4);
  float* vecb = (float*)alloc((size_t)E*3*4);
  float* rb   = (float*)alloc((size_t)E*4);
  float* Yb   = (float*)alloc((size_t)E*16*4);
  float* dYb  = (float*)alloc((size_t)E*48*4);
  float* efb  = (float*)alloc((size_t)E*8*4);
  float* defb = (float*)alloc((size_t)E*8*4);
  float* wb   = (float*)alloc((size_t)E*512*4);
  float* A0   = (float*)alloc((size_t)N*2048*4);
  float* A1   = (float*)alloc((size_t)N*2048*4);
  float* aggb = (float*)alloc((size_t)N*2048*4);  // fwd agg / bwd gagg
  float* gAb  = (float*)alloc((size_t)N*2048*4);
  float* Bbuf = (float*)alloc((size_t)N*KCH*4);
  float* gh1  = (float*)alloc((size_t)N*KCH*4);
  float* ghup = (float*)alloc((size_t)N*KCH*4);
  float* gB0b = (float*)alloc((size_t)N*KCH*4);
  float* gB1v = (float*)alloc((size_t)KCH*4);
  float* gvecb= (float*)alloc((size_t)E*3*4);
  float* C1b  = (float*)alloc((size_t)NELEM*KCH*16*4);
  float* C2Sb = (float*)alloc((size_t)NELEM*KCH*256*4);
  float* Tb   = (float*)alloc((size_t)NELEM*KCH*4096*4);
  float* U2s  = (float*)alloc(1024*4);
  float* U3s  = (float*)alloc(32768*4);
  float* WupT1   = (float*)alloc(16384*4);
  float* WprodT0 = (float*)alloc(16384*4);
  float* WskipT1 = (float*)alloc((size_t)NELEM*16384*4);
  float* WlinT   = (float*)alloc((size_t)8*16384*4);
  float* Wr3T0   = (float*)alloc(32768*4);
  float* Wr3T1   = (float*)alloc(32768*4);
  float* Wr2T0   = (float*)alloc(4096*4);
  float* Wr2T1   = (float*)alloc(4096*4);
  if(off > ws_size) return; // insufficient workspace
  // optional second w buffer (keeps layer-0 w alive -> skips one radial_w recompute)
  float* wb1 = wb; int have_wb1 = 0;
  if(off + (size_t)E*512*4 <= ws_size){ wb1 = (float*)alloc((size_t)E*512*4); have_wb1 = 1; }

  const int KK = KCH*KCH;           // 16384
  dim3 b256(256), b128(128);
  #define GR(n) dim3(((n)+255)/256)

  // zeros
  k_zero<<<GR(out_size),b256,0,stream>>>(out, out_size);
  k_zero<<<GR(N),b256,0,stream>>>((float*)rcnt, N);
  k_zero<<<GR(N),b256,0,stream>>>((float*)rcur, N);
  k_zero<<<GR(NELEM),b256,0,stream>>>((float*)ecnt, NELEM);
  k_zero<<<GR(NELEM),b256,0,stream>>>((float*)ecur, NELEM);
  k_zero<<<GR(N*KCH),b256,0,stream>>>(gh1, N*KCH);
  k_zero<<<GR(N*KCH),b256,0,stream>>>(ghup, N*KCH);
  k_zero<<<GR(E*3),b256,0,stream>>>(gvecb, E*3);

  // elem + embed
  k_elem<<<GR(N),b256,0,stream>>>(attrs, elem, N);
  k_h0<<<GR(N*KCH),b256,0,stream>>>(Wemb, elem, h0, N);

  // CSR by recv
  k_hist<<<GR(E),b256,0,stream>>>(ei+E, rcnt, E);
  k_scan<<<1,b256,0,stream>>>(rcnt, rptr, N);
  k_scatter<<<GR(E),b256,0,stream>>>(ei+E, rptr, rcur, ridx, E);
  // node lists by element
  k_hist<<<GR(N),b256,0,stream>>>(elem, ecnt, N);
  k_scan<<<1,b256,0,stream>>>(ecnt, eptr, NELEM);
  k_scatter<<<GR(N),b256,0,stream>>>(elem, eptr, ecur, eidx, N);

  // transposes
  k_tb<<<GR(KK),b256,0,stream>>>(Wup + KK, WupT1, 1);
  k_tb<<<GR(KK),b256,0,stream>>>(Wprod, WprodT0, 1);
  k_tb<<<GR(NELEM*KK),b256,0,stream>>>(Wskip + (size_t)NELEM*KK, WskipT1, NELEM);
  k_tb<<<GR(8*KK),b256,0,stream>>>(Wlin, WlinT, 8);
  k_tr<<<GR(32768),b256,0,stream>>>(Wr3, Wr3T0, 64, 512);
  k_tr<<<GR(32768),b256,0,stream>>>(Wr3 + 32768, Wr3T1, 64, 512);
  k_tr<<<GR(4096),b256,0,stream>>>(Wr2, Wr2T0, 64, 64);
  k_tr<<<GR(4096),b256,0,stream>>>(Wr2 + 4096, Wr2T1, 64, 64);

  // symmetrized U
  k_symU2<<<GR(1024),b256,0,stream>>>(U2, U2s);
  k_symU3<<<GR(32768),b256,0,stream>>>(U3, U3s);
  k_gB1<<<1,b128,0,stream>>>(Wro, Wprod + KK, gB1v);

  // edge geometry
  k_edge_geom<<<GR(E),b256,0,stream>>>(pos, shifts, ei, E, vecb, rb, Yb, dYb, efb, defb);

  dim3 mmG((N+7)/8);
  dim3 mixG((N+7)/8, 16);
  dim3 polyG(NELEM*KCH);
  dim3 rwG((E+15)/16);
  dim3 ebG((E+3)/4);

  // ---------- layer 0 forward ----------
  k_C1 <<<GR(NELEM*KCH*16),  b256,0,stream>>>(U1,  Wc1, C1b);
  k_C2S<<<GR(NELEM*KCH*256), b256,0,stream>>>(U2s, Wc2, C2Sb);
  k_T  <<<GR(NELEM*KCH*4096),b256,0,stream>>>(U3s, Wc3, Tb);
  k_mm<<<mmG,b128,0,stream>>>(h0, Wup, hup0, N, 0);
  k_radial_w<<<rwG,b256,0,stream>>>(efb, Wr1, Wr2, Wr3, wb, E);
  k_gather<<<dim3(N),b256,0,stream>>>(hup0, wb, Yb, rptr, ridx, ei, aggb, E);
  k_mixed<<<mixG,b128,0,stream>>>(aggb, h0, elem, Wlin, Wskip, A0, N, 1);
  k_poly_fwd<<<polyG,b256,0,stream>>>(A0, C1b, C2Sb, Tb, eptr, eidx, Bbuf);
  k_mm<<<mmG,b128,0,stream>>>(Bbuf, Wprod, h1, N, 0);

  // ---------- layer 1 forward ----------
  k_C1 <<<GR(NELEM*KCH*16),  b256,0,stream>>>(U1,  Wc1 + NELEM*2*KCH, C1b);
  k_C2S<<<GR(NELEM*KCH*256), b256,0,stream>>>(U2s, Wc2 + NELEM*4*KCH, C2Sb);
  k_T  <<<GR(NELEM*KCH*4096),b256,0,stream>>>(U3s, Wc3 + NELEM*8*KCH, Tb);
  k_mm<<<mmG,b128,0,stream>>>(h1, Wup + KK, hup1, N, 0);
  k_radial_w<<<rwG,b256,0,stream>>>(efb, Wr1 + 512, Wr2 + 4096, Wr3 + 32768, wb1, E);
  k_gather<<<dim3(N),b256,0,stream>>>(hup1, wb1, Yb, rptr, ridx, ei, aggb, E);
  k_mixed<<<mixG,b128,0,stream>>>(aggb, h1, elem, Wlin + 4*KK, Wskip + (size_t)NELEM*KK, A1, N, 1);
  k_poly_fwd<<<polyG,b256,0,stream>>>(A1, C1b, C2Sb, Tb, eptr, eidx, Bbuf);
  k_mm<<<mmG,b128,0,stream>>>(Bbuf, Wprod + KK, h2, N, 0);

  // energy
  k_energy<<<GR(N),b256,0,stream>>>(h2, Wro, AE, elem, batch, out, N);

  // ---------- layer 1 backward (C buffers currently hold layer 1) ----------
  k_poly_bwd<<<polyG,b256,0,stream>>>(A1, C1b, C2Sb, Tb, eptr, eidx, gB1v, nullptr, gAb);
  k_mixed<<<mixG,b128,0,stream>>>(gAb, nullptr, elem, WlinT + 4*KK, nullptr, aggb, N, 0);
  k_skip_bwd<<<dim3(N),b128,0,stream>>>(gAb, WskipT1, elem, gh1);
  k_edge_bwd2<<<ebG,b256,0,stream>>>(aggb, hup1, wb1, Yb, dYb, vecb, rb, efb, defb,
                                     Wr1 + 512, Wr2 + 4096, Wr2T1, Wr3T1, ei, E, ghup, gvecb, 1);
  k_mm<<<mmG,b128,0,stream>>>(ghup, WupT1, gh1, N, 1);

  // ---------- layer 0 backward ----------
  k_C1 <<<GR(NELEM*KCH*16),  b256,0,stream>>>(U1,  Wc1, C1b);
  k_C2S<<<GR(NELEM*KCH*256), b256,0,stream>>>(U2s, Wc2, C2Sb);
  k_T  <<<GR(NELEM*KCH*4096),b256,0,stream>>>(U3s, Wc3, Tb);
  k_mm<<<mmG,b128,0,stream>>>(gh1, WprodT0, gB0b, N, 0);
  k_poly_bwd<<<polyG,b256,0,stream>>>(A0, C1b, C2Sb, Tb, eptr, eidx, nullptr, gB0b, gAb);
  k_mixed<<<mixG,b128,0,stream>>>(gAb, nullptr, elem, WlinT, nullptr, aggb, N, 0);
  if(!have_wb1)
    k_radial_w<<<rwG,b256,0,stream>>>(efb, Wr1, Wr2, Wr3, wb, E);
  k_edge_bwd2<<<ebG,b256,0,stream>>>(aggb, hup0, wb, Yb, dYb, vecb, rb, efb, defb,
                                     Wr1, Wr2, Wr2T0, Wr3T0, ei, E, ghup, gvecb, 0);

  // forces
  k_forces<<<GR(E*3),b256,0,stream>>>(gvecb, ei, E, out + G);
  #undef GR
}